// Round 1
// baseline (1046.200 us; speedup 1.0000x reference)
//
#include <hip/hip_runtime.h>
#include <hip/hip_bf16.h>
#include <math.h>

#define BB 16
#define NN 4096
#define SS 512
#define KK 32
#define CC 64

// ---------------------------------------------------------------------------
// Kernel 1: farthest point sampling. One block per batch, 512 threads.
// xyz staged in LDS; per-thread running min-distance in registers.
// Replicates jnp: dist = ((dx*dx + dy*dy) + dz*dz), distance=min, argmax first-index.
// ---------------------------------------------------------------------------
__global__ __launch_bounds__(512) void fps_kernel(const float* __restrict__ xyz,
                                                  float* __restrict__ newxyz) {
#pragma clang fp contract(off)
  const int b = blockIdx.x, tid = threadIdx.x;
  __shared__ float sx[NN], sy[NN], sz[NN];
  __shared__ float wbv[8];
  __shared__ int wbi[8];
  __shared__ int s_cur;
  const float* base = xyz + (size_t)b * NN * 3;
  for (int p = tid; p < NN; p += 512) {
    sx[p] = base[3 * p + 0];
    sy[p] = base[3 * p + 1];
    sz[p] = base[3 * p + 2];
  }
  __syncthreads();
  float px[8], py[8], pz[8], d[8];
#pragma unroll
  for (int j = 0; j < 8; j++) {
    int p = tid + 512 * j;
    px[j] = sx[p]; py[j] = sy[p]; pz[j] = sz[p];
    d[j] = 1e10f;
  }
  int cur = 0;
  for (int it = 0; it < SS; it++) {
    float cx = sx[cur], cy = sy[cur], cz = sz[cur];
    if (tid == 0) {
      float* o = newxyz + ((size_t)b * SS + it) * 3;
      o[0] = cx; o[1] = cy; o[2] = cz;
    }
    float bv = -1.0f; int bi = 0;
#pragma unroll
    for (int j = 0; j < 8; j++) {
      float dx = px[j] - cx, dy = py[j] - cy, dz = pz[j] - cz;
      float t0 = dx * dx, t1 = dy * dy, t2 = dz * dz;
      float dd = (t0 + t1) + t2;
      float nd = fminf(d[j], dd);
      d[j] = nd;
      int p = tid + 512 * j;
      if (nd > bv || (nd == bv && p < bi)) { bv = nd; bi = p; }
    }
    // wave (64-lane) argmax reduce, tie -> smaller index
    for (int off = 1; off < 64; off <<= 1) {
      float ov = __shfl_xor(bv, off);
      int oi = __shfl_xor(bi, off);
      if (ov > bv || (ov == bv && oi < bi)) { bv = ov; bi = oi; }
    }
    if ((tid & 63) == 0) { wbv[tid >> 6] = bv; wbi[tid >> 6] = bi; }
    __syncthreads();
    if (tid == 0) {
      float fbv = wbv[0]; int fbi = wbi[0];
      for (int i = 1; i < 8; i++) {
        if (wbv[i] > fbv || (wbv[i] == fbv && wbi[i] < fbi)) { fbv = wbv[i]; fbi = wbi[i]; }
      }
      s_cur = fbi;
    }
    __syncthreads();
    cur = s_cur;
  }
}

// ---------------------------------------------------------------------------
// Kernel 2: ball query. One block per (b,s) center, 256 threads.
// Replicates: d = ((-2*dot) + |c|^2) + |x|^2 ; mask = d > 0.04f.
// Selected SET = (up to 32 nearest in-radius points, ties by index) filled with
// lowest-index out-of-radius points (all within first 64 indices when cnt<=32).
// Order within the group does not matter (max-pool downstream).
// ---------------------------------------------------------------------------
__global__ __launch_bounds__(256) void ballq_kernel(const float* __restrict__ xyz,
                                                    const float* __restrict__ newxyz,
                                                    int* __restrict__ gidx) {
#pragma clang fp contract(off)
  const int bs = blockIdx.x;
  const int b = bs >> 9;
  const int tid = threadIdx.x;
  __shared__ unsigned long long keys[NN];
  __shared__ int s_cnt;
  __shared__ unsigned char inflag[64];
  __shared__ int outg[KK];
  __shared__ unsigned long long rk[4];
  __shared__ int rp[4];
  if (tid == 0) s_cnt = 0;
  __syncthreads();
  const float cx = newxyz[bs * 3 + 0];
  const float cy = newxyz[bs * 3 + 1];
  const float cz = newxyz[bs * 3 + 2];
  const float csq = (cx * cx + cy * cy) + cz * cz;
  const float* base = xyz + (size_t)b * NN * 3;
  const float R2 = 0.04f;
  for (int j = 0; j < 16; j++) {
    const int p = tid + 256 * j;
    float x = base[3 * p + 0], y = base[3 * p + 1], z = base[3 * p + 2];
    float dot = (cx * x + cy * y) + cz * z;
    float ssq = (x * x + y * y) + z * z;
    float dsq = ((-2.0f * dot) + csq) + ssq;
    bool in = !(dsq > R2);
    if (p < 64) inflag[p] = in ? (unsigned char)1 : (unsigned char)0;
    if (in) {
      int pos = atomicAdd(&s_cnt, 1);
      unsigned u = __float_as_uint(dsq);
      u ^= (u >> 31) ? 0xFFFFFFFFu : 0x80000000u;  // monotonic key (handles tiny negatives)
      keys[pos] = ((unsigned long long)u << 32) | (unsigned)p;
    }
  }
  __syncthreads();
  const int cnt = s_cnt;

  if (NN - cnt < KK) {
    // reference cond branch: whole group = nearest point (min key). ~never taken.
    unsigned long long mk = ~0ull; int mp = -1;
    for (int i = tid; i < cnt; i += 256)
      if (keys[i] < mk) { mk = keys[i]; mp = i; }
    for (int off = 1; off < 64; off <<= 1) {
      unsigned long long ok = __shfl_xor(mk, off);
      int op = __shfl_xor(mp, off);
      if (ok < mk) { mk = ok; mp = op; }
    }
    if ((tid & 63) == 0) { rk[tid >> 6] = mk; rp[tid >> 6] = mp; }
    __syncthreads();
    if (tid == 0) {
      unsigned long long fm = rk[0];
      for (int i = 1; i < 4; i++) if (rk[i] < fm) fm = rk[i];
      int idx = (int)(fm & 0xFFFFFFFFull);
      for (int i = 0; i < KK; i++) outg[i] = idx;
    }
  } else if (cnt <= KK) {
    // fast path: all in-radius + lowest-index out-of-radius fill (from first 64).
    if (tid < cnt && tid < KK) outg[tid] = (int)(keys[tid] & 0xFFFFFFFFull);
    if (tid == 0) {
      int pos = cnt;
      for (int i = 0; i < 64 && pos < KK; i++)
        if (!inflag[i]) outg[pos++] = i;
    }
  } else {
    // rare: more than 32 in radius -> 32 smallest (dist,idx) keys.
    for (int r = 0; r < KK; r++) {
      unsigned long long mk = ~0ull; int mp = -1;
      for (int i = tid; i < cnt; i += 256)
        if (keys[i] < mk) { mk = keys[i]; mp = i; }
      for (int off = 1; off < 64; off <<= 1) {
        unsigned long long ok = __shfl_xor(mk, off);
        int op = __shfl_xor(mp, off);
        if (ok < mk) { mk = ok; mp = op; }
      }
      if ((tid & 63) == 0) { rk[tid >> 6] = mk; rp[tid >> 6] = mp; }
      __syncthreads();
      if (tid == 0) {
        unsigned long long fm = rk[0]; int fp = rp[0];
        for (int i = 1; i < 4; i++) if (rk[i] < fm) { fm = rk[i]; fp = rp[i]; }
        outg[r] = (int)(fm & 0xFFFFFFFFull);
        keys[fp] = ~0ull;
      }
      __syncthreads();
    }
  }
  __syncthreads();
  if (tid < KK) gidx[(size_t)bs * KK + tid] = outg[tid];
}

// ---------------------------------------------------------------------------
// Kernel 3: gather + 3x (affine with folded BN + ReLU) + max over k.
// One block per 4 centers (128 rows), 256 threads, 8k x 4oc register tiles.
// ---------------------------------------------------------------------------
template <int CIN, int COUT, bool LAST>
__device__ __forceinline__ void do_layer(
    const int tid, float (*Xb)[68], float (*Wb)[69],
    float* sa, float* sbv, float (*mm)[4],
    const float* __restrict__ w, const float* __restrict__ bb,
    const float* __restrict__ gg, const float* __restrict__ be,
    const float* __restrict__ rm, const float* __restrict__ rv,
    float* __restrict__ out2, const int bs0) {
  if (tid < COUT) {
    float a = gg[tid] / sqrtf(rv[tid] + 1e-5f);
    sa[tid] = a;
    sbv[tid] = (bb[tid] - rm[tid]) * a + be[tid];
  }
  __syncthreads();
  for (int i = tid; i < COUT * CIN; i += 256) {
    int oc = i / CIN;
    int c = i - oc * CIN;
    Wb[oc][c] = w[i] * sa[oc];
  }
  if constexpr (CIN == 67) {
    if (tid < COUT) Wb[tid][67] = 0.0f;
  }
  __syncthreads();
  constexpr int CQ = (CIN + 3) >> 2;
  const int ktile = tid >> 4;
  const int octile = tid & 15;
  const int k0 = ktile * 8;
  constexpr int NPASS = LAST ? 2 : 1;
  for (int pass = 0; pass < NPASS; pass++) {
    float acc[8][4];
#pragma unroll
    for (int i = 0; i < 8; i++)
#pragma unroll
      for (int j = 0; j < 4; j++) acc[i][j] = 0.0f;
    const int ocb = octile * 4 + pass * 64;
    for (int q = 0; q < CQ; q++) {
      float4 xq[8];
#pragma unroll
      for (int i = 0; i < 8; i++)
        xq[i] = *reinterpret_cast<const float4*>(&Xb[k0 + i][q * 4]);
#pragma unroll
      for (int j = 0; j < 4; j++) {
        const float* wr = &Wb[ocb + j][q * 4];
        float w0_ = wr[0], w1_ = wr[1], w2_ = wr[2], w3_ = wr[3];
#pragma unroll
        for (int i = 0; i < 8; i++) {
          float a_ = acc[i][j];
          a_ = fmaf(xq[i].x, w0_, a_);
          a_ = fmaf(xq[i].y, w1_, a_);
          a_ = fmaf(xq[i].z, w2_, a_);
          a_ = fmaf(xq[i].w, w3_, a_);
          acc[i][j] = a_;
        }
      }
    }
    if constexpr (!LAST) {
      __syncthreads();  // all reads of Xb done before in-place overwrite
#pragma unroll
      for (int j = 0; j < 4; j++) {
        float bias = sbv[ocb + j];
#pragma unroll
        for (int i = 0; i < 8; i++)
          Xb[k0 + i][ocb + j] = fmaxf(acc[i][j] + bias, 0.0f);
      }
      __syncthreads();
    } else {
#pragma unroll
      for (int j = 0; j < 4; j++) {
        float bias = sbv[ocb + j];
        float m = 0.0f;
#pragma unroll
        for (int i = 0; i < 8; i++)
          m = fmaxf(m, fmaxf(acc[i][j] + bias, 0.0f));
        mm[tid][j] = m;
      }
      __syncthreads();
      {
        const int ci = tid >> 6;     // local center 0..3
        const int olane = tid & 63;  // oc within pass
        const int oct = olane >> 2, jj = olane & 3;
        float m = 0.0f;
#pragma unroll
        for (int r = 0; r < 4; r++)
          m = fmaxf(m, mm[(ci * 4 + r) * 16 + oct][jj]);
        out2[((size_t)(bs0 + ci)) * 128 + pass * 64 + olane] = m;
      }
      __syncthreads();  // mm reused by next pass
    }
  }
}

__global__ __launch_bounds__(256, 2) void mlp_kernel(
    const float* __restrict__ xyz, const float* __restrict__ points,
    const float* __restrict__ newxyz, const int* __restrict__ gidx,
    const float* __restrict__ w0, const float* __restrict__ b0,
    const float* __restrict__ g0, const float* __restrict__ be0,
    const float* __restrict__ rm0, const float* __restrict__ rv0,
    const float* __restrict__ w1, const float* __restrict__ b1,
    const float* __restrict__ g1, const float* __restrict__ be1,
    const float* __restrict__ rm1, const float* __restrict__ rv1,
    const float* __restrict__ w2, const float* __restrict__ b2,
    const float* __restrict__ g2, const float* __restrict__ be2,
    const float* __restrict__ rm2, const float* __restrict__ rv2,
    float* __restrict__ out2) {
  const int tid = threadIdx.x;
  const int bs0 = blockIdx.x * 4;
  const int b = bs0 >> 9;
  __shared__ float Xb[128][68];
  __shared__ float Wb[128][69];
  __shared__ float sa[128], sbv[128];
  __shared__ float mm[256][4];
  __shared__ int sg[128];
  if (tid < 128) sg[tid] = gidx[(size_t)bs0 * KK + tid];
  __syncthreads();
  // gather point features (coalesced 64-float runs)
  for (int i = tid; i < 128 * 64; i += 256) {
    int r = i >> 6, c = i & 63;
    Xb[r][3 + c] = points[((size_t)b * NN + sg[r]) * CC + c];
  }
  // gather xyz and subtract center; zero the pad column
  if (tid < 128) {
    int ci = tid >> 5;
    int g = sg[tid];
    const float* cp = newxyz + ((size_t)bs0 + ci) * 3;
    const float* pp = xyz + ((size_t)b * NN + g) * 3;
    Xb[tid][0] = pp[0] - cp[0];
    Xb[tid][1] = pp[1] - cp[1];
    Xb[tid][2] = pp[2] - cp[2];
    Xb[tid][67] = 0.0f;
  }
  // (first barrier inside do_layer covers the gather writes)
  do_layer<67, 64, false>(tid, Xb, Wb, sa, sbv, mm, w0, b0, g0, be0, rm0, rv0, nullptr, bs0);
  do_layer<64, 64, false>(tid, Xb, Wb, sa, sbv, mm, w1, b1, g1, be1, rm1, rv1, nullptr, bs0);
  do_layer<64, 128, true>(tid, Xb, Wb, sa, sbv, mm, w2, b2, g2, be2, rm2, rv2, out2, bs0);
}

// ---------------------------------------------------------------------------
extern "C" void kernel_launch(void* const* d_in, const int* in_sizes, int n_in,
                              void* d_out, int out_size, void* d_ws, size_t ws_size,
                              hipStream_t stream) {
  const float* xyz = (const float*)d_in[0];
  const float* points = (const float*)d_in[1];
  const float* w0 = (const float*)d_in[2];
  const float* b0 = (const float*)d_in[3];
  const float* g0 = (const float*)d_in[4];
  const float* be0 = (const float*)d_in[5];
  const float* rm0 = (const float*)d_in[6];
  const float* rv0 = (const float*)d_in[7];
  const float* w1 = (const float*)d_in[8];
  const float* b1 = (const float*)d_in[9];
  const float* g1 = (const float*)d_in[10];
  const float* be1 = (const float*)d_in[11];
  const float* rm1 = (const float*)d_in[12];
  const float* rv1 = (const float*)d_in[13];
  const float* w2 = (const float*)d_in[14];
  const float* b2 = (const float*)d_in[15];
  const float* g2 = (const float*)d_in[16];
  const float* be2 = (const float*)d_in[17];
  const float* rm2 = (const float*)d_in[18];
  const float* rv2 = (const float*)d_in[19];

  float* newxyz = (float*)d_out;                       // (B, 512, 3)
  float* out2 = (float*)d_out + (size_t)BB * SS * 3;   // (B, 512, 128)
  int* gidx = (int*)d_ws;                              // (B, 512, 32)

  fps_kernel<<<BB, 512, 0, stream>>>(xyz, newxyz);
  ballq_kernel<<<BB * SS, 256, 0, stream>>>(xyz, newxyz, gidx);
  mlp_kernel<<<(BB * SS) / 4, 256, 0, stream>>>(
      xyz, points, newxyz, gidx,
      w0, b0, g0, be0, rm0, rv0,
      w1, b1, g1, be1, rm1, rv1,
      w2, b2, g2, be2, rm2, rv2,
      out2);
}

// Round 2
// 583.489 us; speedup vs baseline: 1.7930x; 1.7930x over previous
//
#include <hip/hip_runtime.h>
#include <hip/hip_bf16.h>
#include <math.h>

#define BB 16
#define NN 4096
#define SS 512
#define KK 32
#define CC 64

// ---------------------------------------------------------------------------
// Kernel 1: farthest point sampling. One block per batch, 512 threads, 8 pts/lane.
// Latency-optimized: no global stores in loop, ONE barrier per iteration
// (parity double-buffered wave partials), u64-packed (dist,idx) argmax keys.
// Replicates jnp: dist = ((dx*dx + dy*dy) + dz*dz), distance=min, argmax first-index.
// ---------------------------------------------------------------------------
__global__ __launch_bounds__(512) void fps_kernel(const float* __restrict__ xyz,
                                                  float* __restrict__ newxyz) {
#pragma clang fp contract(off)
  const int b = blockIdx.x, tid = threadIdx.x;
  __shared__ float sx[NN], sy[NN], sz[NN];
  __shared__ unsigned long long pk[2][8];
  __shared__ int sel[SS];
  const float* base = xyz + (size_t)b * NN * 3;
  for (int p = tid; p < NN; p += 512) {
    sx[p] = base[3 * p + 0];
    sy[p] = base[3 * p + 1];
    sz[p] = base[3 * p + 2];
  }
  if (tid == 0) sel[0] = 0;
  __syncthreads();
  float px[8], py[8], pz[8], d[8];
#pragma unroll
  for (int j = 0; j < 8; j++) {
    int p = tid + 512 * j;
    px[j] = sx[p]; py[j] = sy[p]; pz[j] = sz[p];
    d[j] = 1e10f;
  }
  int cur = 0;
  // Reference emits `farthest` BEFORE each update; 512 outputs need only 511
  // argmax steps (sel[0] = 0).
  for (int it = 0; it < SS - 1; it++) {
    const float cx = sx[cur], cy = sy[cur], cz = sz[cur];
    float bv = -1.0f;
    int bi = 0;
#pragma unroll
    for (int j = 0; j < 8; j++) {
      float dx = px[j] - cx, dy = py[j] - cy, dz = pz[j] - cz;
      float t0 = dx * dx, t1 = dy * dy, t2 = dz * dz;
      float dd = (t0 + t1) + t2;
      float nd = fminf(d[j], dd);
      d[j] = nd;
      // strict > with increasing p keeps the smallest index on ties
      if (nd > bv) { bv = nd; bi = tid + 512 * j; }
    }
    // pack: non-negative f32 bits are order-monotone; lo = NN-1-p so that
    // equal distances pick the SMALLER point index (jnp.argmax first-match).
    unsigned long long key =
        ((unsigned long long)__float_as_uint(bv) << 32) | (unsigned)(NN - 1 - bi);
#pragma unroll
    for (int off = 1; off < 64; off <<= 1) {
      unsigned long long ok = __shfl_xor(key, off);
      key = ok > key ? ok : key;
    }
    const int par = it & 1;
    if ((tid & 63) == 0) pk[par][tid >> 6] = key;
    __syncthreads();
    unsigned long long bk = pk[par][0];
#pragma unroll
    for (int i = 1; i < 8; i++) {
      unsigned long long k2 = pk[par][i];
      bk = k2 > bk ? k2 : bk;
    }
    cur = NN - 1 - (int)(bk & 0xFFFFFFFFull);
    if (tid == 0) sel[it + 1] = cur;
  }
  __syncthreads();
  for (int i = tid; i < SS * 3; i += 512) {
    int s = i / 3, c = i - s * 3;
    int g = sel[s];
    float v = (c == 0) ? sx[g] : (c == 1) ? sy[g] : sz[g];
    newxyz[((size_t)b * SS + s) * 3 + c] = v;
  }
}

// ---------------------------------------------------------------------------
// Kernel 2: ball query. One block per (b,s) center, 256 threads.
// Replicates: d = ((-2*dot) + |c|^2) + |x|^2 ; mask = d > 0.04f.
// Selected SET = (up to 32 nearest in-radius points, ties by index) filled with
// lowest-index out-of-radius points (all within first 64 indices when cnt<=32).
// Order within the group does not matter (max-pool downstream).
// ---------------------------------------------------------------------------
__global__ __launch_bounds__(256) void ballq_kernel(const float* __restrict__ xyz,
                                                    const float* __restrict__ newxyz,
                                                    int* __restrict__ gidx) {
#pragma clang fp contract(off)
  const int bs = blockIdx.x;
  const int b = bs >> 9;
  const int tid = threadIdx.x;
  __shared__ unsigned long long keys[NN];
  __shared__ int s_cnt;
  __shared__ unsigned char inflag[64];
  __shared__ int outg[KK];
  __shared__ unsigned long long rk[4];
  __shared__ int rp[4];
  if (tid == 0) s_cnt = 0;
  __syncthreads();
  const float cx = newxyz[bs * 3 + 0];
  const float cy = newxyz[bs * 3 + 1];
  const float cz = newxyz[bs * 3 + 2];
  const float csq = (cx * cx + cy * cy) + cz * cz;
  const float* base = xyz + (size_t)b * NN * 3;
  const float R2 = 0.04f;
  for (int j = 0; j < 16; j++) {
    const int p = tid + 256 * j;
    float x = base[3 * p + 0], y = base[3 * p + 1], z = base[3 * p + 2];
    float dot = (cx * x + cy * y) + cz * z;
    float ssq = (x * x + y * y) + z * z;
    float dsq = ((-2.0f * dot) + csq) + ssq;
    bool in = !(dsq > R2);
    if (p < 64) inflag[p] = in ? (unsigned char)1 : (unsigned char)0;
    if (in) {
      int pos = atomicAdd(&s_cnt, 1);
      unsigned u = __float_as_uint(dsq);
      u ^= (u >> 31) ? 0xFFFFFFFFu : 0x80000000u;  // monotonic key (handles tiny negatives)
      keys[pos] = ((unsigned long long)u << 32) | (unsigned)p;
    }
  }
  __syncthreads();
  const int cnt = s_cnt;

  if (NN - cnt < KK) {
    // reference cond branch: whole group = nearest point (min key). ~never taken.
    unsigned long long mk = ~0ull; int mp = -1;
    for (int i = tid; i < cnt; i += 256)
      if (keys[i] < mk) { mk = keys[i]; mp = i; }
    for (int off = 1; off < 64; off <<= 1) {
      unsigned long long ok = __shfl_xor(mk, off);
      int op = __shfl_xor(mp, off);
      if (ok < mk) { mk = ok; mp = op; }
    }
    if ((tid & 63) == 0) { rk[tid >> 6] = mk; rp[tid >> 6] = mp; }
    __syncthreads();
    if (tid == 0) {
      unsigned long long fm = rk[0];
      for (int i = 1; i < 4; i++) if (rk[i] < fm) fm = rk[i];
      int idx = (int)(fm & 0xFFFFFFFFull);
      for (int i = 0; i < KK; i++) outg[i] = idx;
    }
  } else if (cnt <= KK) {
    // fast path: all in-radius + lowest-index out-of-radius fill (from first 64).
    if (tid < cnt && tid < KK) outg[tid] = (int)(keys[tid] & 0xFFFFFFFFull);
    if (tid == 0) {
      int pos = cnt;
      for (int i = 0; i < 64 && pos < KK; i++)
        if (!inflag[i]) outg[pos++] = i;
    }
  } else {
    // rare: more than 32 in radius -> 32 smallest (dist,idx) keys.
    for (int r = 0; r < KK; r++) {
      unsigned long long mk = ~0ull; int mp = -1;
      for (int i = tid; i < cnt; i += 256)
        if (keys[i] < mk) { mk = keys[i]; mp = i; }
      for (int off = 1; off < 64; off <<= 1) {
        unsigned long long ok = __shfl_xor(mk, off);
        int op = __shfl_xor(mp, off);
        if (ok < mk) { mk = ok; mp = op; }
      }
      if ((tid & 63) == 0) { rk[tid >> 6] = mk; rp[tid >> 6] = mp; }
      __syncthreads();
      if (tid == 0) {
        unsigned long long fm = rk[0]; int fp = rp[0];
        for (int i = 1; i < 4; i++) if (rk[i] < fm) { fm = rk[i]; fp = rp[i]; }
        outg[r] = (int)(fm & 0xFFFFFFFFull);
        keys[fp] = ~0ull;
      }
      __syncthreads();
    }
  }
  __syncthreads();
  if (tid < KK) gidx[(size_t)bs * KK + tid] = outg[tid];
}

// ---------------------------------------------------------------------------
// Kernel 3: gather + 3x (affine with folded BN + ReLU) + max over k.
// One block per 4 centers (128 rows), 256 threads, 8k x 4oc register tiles.
// ---------------------------------------------------------------------------
template <int CIN, int COUT, bool LAST>
__device__ __forceinline__ void do_layer(
    const int tid, float (*Xb)[68], float (*Wb)[69],
    float* sa, float* sbv, float (*mm)[4],
    const float* __restrict__ w, const float* __restrict__ bb,
    const float* __restrict__ gg, const float* __restrict__ be,
    const float* __restrict__ rm, const float* __restrict__ rv,
    float* __restrict__ out2, const int bs0) {
  if (tid < COUT) {
    float a = gg[tid] / sqrtf(rv[tid] + 1e-5f);
    sa[tid] = a;
    sbv[tid] = (bb[tid] - rm[tid]) * a + be[tid];
  }
  __syncthreads();
  for (int i = tid; i < COUT * CIN; i += 256) {
    int oc = i / CIN;
    int c = i - oc * CIN;
    Wb[oc][c] = w[i] * sa[oc];
  }
  if constexpr (CIN == 67) {
    if (tid < COUT) Wb[tid][67] = 0.0f;
  }
  __syncthreads();
  constexpr int CQ = (CIN + 3) >> 2;
  const int ktile = tid >> 4;
  const int octile = tid & 15;
  const int k0 = ktile * 8;
  constexpr int NPASS = LAST ? 2 : 1;
  for (int pass = 0; pass < NPASS; pass++) {
    float acc[8][4];
#pragma unroll
    for (int i = 0; i < 8; i++)
#pragma unroll
      for (int j = 0; j < 4; j++) acc[i][j] = 0.0f;
    const int ocb = octile * 4 + pass * 64;
    for (int q = 0; q < CQ; q++) {
      float4 xq[8];
#pragma unroll
      for (int i = 0; i < 8; i++)
        xq[i] = *reinterpret_cast<const float4*>(&Xb[k0 + i][q * 4]);
#pragma unroll
      for (int j = 0; j < 4; j++) {
        const float* wr = &Wb[ocb + j][q * 4];
        float w0_ = wr[0], w1_ = wr[1], w2_ = wr[2], w3_ = wr[3];
#pragma unroll
        for (int i = 0; i < 8; i++) {
          float a_ = acc[i][j];
          a_ = fmaf(xq[i].x, w0_, a_);
          a_ = fmaf(xq[i].y, w1_, a_);
          a_ = fmaf(xq[i].z, w2_, a_);
          a_ = fmaf(xq[i].w, w3_, a_);
          acc[i][j] = a_;
        }
      }
    }
    if constexpr (!LAST) {
      __syncthreads();  // all reads of Xb done before in-place overwrite
#pragma unroll
      for (int j = 0; j < 4; j++) {
        float bias = sbv[ocb + j];
#pragma unroll
        for (int i = 0; i < 8; i++)
          Xb[k0 + i][ocb + j] = fmaxf(acc[i][j] + bias, 0.0f);
      }
      __syncthreads();
    } else {
#pragma unroll
      for (int j = 0; j < 4; j++) {
        float bias = sbv[ocb + j];
        float m = 0.0f;
#pragma unroll
        for (int i = 0; i < 8; i++)
          m = fmaxf(m, fmaxf(acc[i][j] + bias, 0.0f));
        mm[tid][j] = m;
      }
      __syncthreads();
      {
        const int ci = tid >> 6;     // local center 0..3
        const int olane = tid & 63;  // oc within pass
        const int oct = olane >> 2, jj = olane & 3;
        float m = 0.0f;
#pragma unroll
        for (int r = 0; r < 4; r++)
          m = fmaxf(m, mm[(ci * 4 + r) * 16 + oct][jj]);
        out2[((size_t)(bs0 + ci)) * 128 + pass * 64 + olane] = m;
      }
      __syncthreads();  // mm reused by next pass
    }
  }
}

__global__ __launch_bounds__(256, 2) void mlp_kernel(
    const float* __restrict__ xyz, const float* __restrict__ points,
    const float* __restrict__ newxyz, const int* __restrict__ gidx,
    const float* __restrict__ w0, const float* __restrict__ b0,
    const float* __restrict__ g0, const float* __restrict__ be0,
    const float* __restrict__ rm0, const float* __restrict__ rv0,
    const float* __restrict__ w1, const float* __restrict__ b1,
    const float* __restrict__ g1, const float* __restrict__ be1,
    const float* __restrict__ rm1, const float* __restrict__ rv1,
    const float* __restrict__ w2, const float* __restrict__ b2,
    const float* __restrict__ g2, const float* __restrict__ be2,
    const float* __restrict__ rm2, const float* __restrict__ rv2,
    float* __restrict__ out2) {
  const int tid = threadIdx.x;
  const int bs0 = blockIdx.x * 4;
  const int b = bs0 >> 9;
  __shared__ float Xb[128][68];
  __shared__ float Wb[128][69];
  __shared__ float sa[128], sbv[128];
  __shared__ float mm[256][4];
  __shared__ int sg[128];
  if (tid < 128) sg[tid] = gidx[(size_t)bs0 * KK + tid];
  __syncthreads();
  // gather point features (coalesced 64-float runs)
  for (int i = tid; i < 128 * 64; i += 256) {
    int r = i >> 6, c = i & 63;
    Xb[r][3 + c] = points[((size_t)b * NN + sg[r]) * CC + c];
  }
  // gather xyz and subtract center; zero the pad column
  if (tid < 128) {
    int ci = tid >> 5;
    int g = sg[tid];
    const float* cp = newxyz + ((size_t)bs0 + ci) * 3;
    const float* pp = xyz + ((size_t)b * NN + g) * 3;
    Xb[tid][0] = pp[0] - cp[0];
    Xb[tid][1] = pp[1] - cp[1];
    Xb[tid][2] = pp[2] - cp[2];
    Xb[tid][67] = 0.0f;
  }
  // (first barrier inside do_layer covers the gather writes)
  do_layer<67, 64, false>(tid, Xb, Wb, sa, sbv, mm, w0, b0, g0, be0, rm0, rv0, nullptr, bs0);
  do_layer<64, 64, false>(tid, Xb, Wb, sa, sbv, mm, w1, b1, g1, be1, rm1, rv1, nullptr, bs0);
  do_layer<64, 128, true>(tid, Xb, Wb, sa, sbv, mm, w2, b2, g2, be2, rm2, rv2, out2, bs0);
}

// ---------------------------------------------------------------------------
extern "C" void kernel_launch(void* const* d_in, const int* in_sizes, int n_in,
                              void* d_out, int out_size, void* d_ws, size_t ws_size,
                              hipStream_t stream) {
  const float* xyz = (const float*)d_in[0];
  const float* points = (const float*)d_in[1];
  const float* w0 = (const float*)d_in[2];
  const float* b0 = (const float*)d_in[3];
  const float* g0 = (const float*)d_in[4];
  const float* be0 = (const float*)d_in[5];
  const float* rm0 = (const float*)d_in[6];
  const float* rv0 = (const float*)d_in[7];
  const float* w1 = (const float*)d_in[8];
  const float* b1 = (const float*)d_in[9];
  const float* g1 = (const float*)d_in[10];
  const float* be1 = (const float*)d_in[11];
  const float* rm1 = (const float*)d_in[12];
  const float* rv1 = (const float*)d_in[13];
  const float* w2 = (const float*)d_in[14];
  const float* b2 = (const float*)d_in[15];
  const float* g2 = (const float*)d_in[16];
  const float* be2 = (const float*)d_in[17];
  const float* rm2 = (const float*)d_in[18];
  const float* rv2 = (const float*)d_in[19];

  float* newxyz = (float*)d_out;                       // (B, 512, 3)
  float* out2 = (float*)d_out + (size_t)BB * SS * 3;   // (B, 512, 128)
  int* gidx = (int*)d_ws;                              // (B, 512, 32)

  fps_kernel<<<BB, 512, 0, stream>>>(xyz, newxyz);
  ballq_kernel<<<BB * SS, 256, 0, stream>>>(xyz, newxyz, gidx);
  mlp_kernel<<<(BB * SS) / 4, 256, 0, stream>>>(
      xyz, points, newxyz, gidx,
      w0, b0, g0, be0, rm0, rv0,
      w1, b1, g1, be1, rm1, rv1,
      w2, b2, g2, be2, rm2, rv2,
      out2);
}

// Round 3
// 562.024 us; speedup vs baseline: 1.8615x; 1.0382x over previous
//
#include <hip/hip_runtime.h>
#include <hip/hip_bf16.h>
#include <math.h>

#define BB 16
#define NN 4096
#define SS 512
#define KK 32
#define CC 64

// ---------------------------------------------------------------------------
// Kernel 1: farthest point sampling. One block per batch, 256 threads, 16 pts/lane,
// LANE-MAJOR point assignment (p = tid*16+j) so argmax ties resolve to the
// smallest point index via lowest-lane/lowest-wave selection.
// One barrier per iteration; f32 shuffle-max + ballot index resolve;
// parity double-buffered wave partials. No global traffic in the loop.
// Replicates jnp: dist = ((dx*dx + dy*dy) + dz*dz), distance=min, argmax first-index.
// ---------------------------------------------------------------------------
__global__ __launch_bounds__(256) void fps_kernel(const float* __restrict__ xyz,
                                                  float* __restrict__ newxyz) {
#pragma clang fp contract(off)
  const int b = blockIdx.x, tid = threadIdx.x;
  const int wid = tid >> 6, lane = tid & 63;
  __shared__ float sx[NN], sy[NN], sz[NN];
  __shared__ float pv[2][4];
  __shared__ int pi[2][4];
  __shared__ int sel[SS];
  const float* base = xyz + (size_t)b * NN * 3;
  for (int p = tid; p < NN; p += 256) {
    sx[p] = base[3 * p + 0];
    sy[p] = base[3 * p + 1];
    sz[p] = base[3 * p + 2];
  }
  if (tid == 0) sel[0] = 0;
  __syncthreads();
  float px[16], py[16], pz[16], d[16];
#pragma unroll
  for (int j = 0; j < 16; j++) {
    int p = tid * 16 + j;
    px[j] = sx[p]; py[j] = sy[p]; pz[j] = sz[p];
    d[j] = 1e10f;
  }
  int cur = 0;
  // Reference emits `farthest` BEFORE each update; 512 outputs need only 511
  // argmax steps (sel[0] = 0).
  for (int it = 0; it < SS - 1; it++) {
    const float cx = sx[cur], cy = sy[cur], cz = sz[cur];
    float bv = -1.0f;
    int bj = 0;
#pragma unroll
    for (int j = 0; j < 16; j++) {
      float dx = px[j] - cx, dy = py[j] - cy, dz = pz[j] - cz;
      float t0 = dx * dx, t1 = dy * dy, t2 = dz * dz;
      float dd = (t0 + t1) + t2;
      float nd = fminf(d[j], dd);
      d[j] = nd;
      // strict > keeps the smallest j (=smallest point index within lane) on ties
      if (nd > bv) { bv = nd; bj = j; }
    }
    const int bi = tid * 16 + bj;
    // wave-level f32 max (exact: fmaxf of non-negative values)
    float m = bv;
#pragma unroll
    for (int off = 1; off < 64; off <<= 1)
      m = fmaxf(m, __shfl_xor(m, off));
    // lowest lane holding the max -> smallest point index (lane-major mapping)
    unsigned long long mask = __ballot(bv == m);
    int src = (int)__builtin_ctzll(mask);
    int wbi = __shfl(bi, src);
    const int par = it & 1;
    if (lane == 0) { pv[par][wid] = m; pi[par][wid] = wbi; }
    __syncthreads();
    // all threads redundantly reduce the 4 wave partials (strict > keeps
    // lowest wave = smallest index on exact ties)
    float fbv = pv[par][0];
    int fbi = pi[par][0];
#pragma unroll
    for (int w = 1; w < 4; w++) {
      float v = pv[par][w];
      int ii = pi[par][w];
      if (v > fbv) { fbv = v; fbi = ii; }
    }
    cur = fbi;
    if (tid == 0) sel[it + 1] = cur;
  }
  __syncthreads();
  for (int i = tid; i < SS * 3; i += 256) {
    int s = i / 3, c = i - s * 3;
    int g = sel[s];
    float v = (c == 0) ? sx[g] : (c == 1) ? sy[g] : sz[g];
    newxyz[((size_t)b * SS + s) * 3 + c] = v;
  }
}

// ---------------------------------------------------------------------------
// Kernel 2: ball query. One block per (b,s) center, 256 threads.
// Replicates: d = ((-2*dot) + |c|^2) + |x|^2 ; mask = d > 0.04f.
// Selected SET = (up to 32 nearest in-radius points, ties by index) filled with
// lowest-index out-of-radius points (all within first 64 indices when cnt<=32).
// Order within the group does not matter (max-pool downstream).
// ---------------------------------------------------------------------------
__global__ __launch_bounds__(256) void ballq_kernel(const float* __restrict__ xyz,
                                                    const float* __restrict__ newxyz,
                                                    int* __restrict__ gidx) {
#pragma clang fp contract(off)
  const int bs = blockIdx.x;
  const int b = bs >> 9;
  const int tid = threadIdx.x;
  __shared__ unsigned long long keys[NN];
  __shared__ int s_cnt;
  __shared__ unsigned char inflag[64];
  __shared__ int outg[KK];
  __shared__ unsigned long long rk[4];
  __shared__ int rp[4];
  if (tid == 0) s_cnt = 0;
  __syncthreads();
  const float cx = newxyz[bs * 3 + 0];
  const float cy = newxyz[bs * 3 + 1];
  const float cz = newxyz[bs * 3 + 2];
  const float csq = (cx * cx + cy * cy) + cz * cz;
  const float* base = xyz + (size_t)b * NN * 3;
  const float R2 = 0.04f;
  for (int j = 0; j < 16; j++) {
    const int p = tid + 256 * j;
    float x = base[3 * p + 0], y = base[3 * p + 1], z = base[3 * p + 2];
    float dot = (cx * x + cy * y) + cz * z;
    float ssq = (x * x + y * y) + z * z;
    float dsq = ((-2.0f * dot) + csq) + ssq;
    bool in = !(dsq > R2);
    if (p < 64) inflag[p] = in ? (unsigned char)1 : (unsigned char)0;
    if (in) {
      int pos = atomicAdd(&s_cnt, 1);
      unsigned u = __float_as_uint(dsq);
      u ^= (u >> 31) ? 0xFFFFFFFFu : 0x80000000u;  // monotonic key (handles tiny negatives)
      keys[pos] = ((unsigned long long)u << 32) | (unsigned)p;
    }
  }
  __syncthreads();
  const int cnt = s_cnt;

  if (NN - cnt < KK) {
    // reference cond branch: whole group = nearest point (min key). ~never taken.
    unsigned long long mk = ~0ull; int mp = -1;
    for (int i = tid; i < cnt; i += 256)
      if (keys[i] < mk) { mk = keys[i]; mp = i; }
    for (int off = 1; off < 64; off <<= 1) {
      unsigned long long ok = __shfl_xor(mk, off);
      int op = __shfl_xor(mp, off);
      if (ok < mk) { mk = ok; mp = op; }
    }
    if ((tid & 63) == 0) { rk[tid >> 6] = mk; rp[tid >> 6] = mp; }
    __syncthreads();
    if (tid == 0) {
      unsigned long long fm = rk[0];
      for (int i = 1; i < 4; i++) if (rk[i] < fm) fm = rk[i];
      int idx = (int)(fm & 0xFFFFFFFFull);
      for (int i = 0; i < KK; i++) outg[i] = idx;
    }
  } else if (cnt <= KK) {
    // fast path: all in-radius + lowest-index out-of-radius fill (from first 64).
    if (tid < cnt && tid < KK) outg[tid] = (int)(keys[tid] & 0xFFFFFFFFull);
    if (tid == 0) {
      int pos = cnt;
      for (int i = 0; i < 64 && pos < KK; i++)
        if (!inflag[i]) outg[pos++] = i;
    }
  } else {
    // rare: more than 32 in radius -> 32 smallest (dist,idx) keys.
    for (int r = 0; r < KK; r++) {
      unsigned long long mk = ~0ull; int mp = -1;
      for (int i = tid; i < cnt; i += 256)
        if (keys[i] < mk) { mk = keys[i]; mp = i; }
      for (int off = 1; off < 64; off <<= 1) {
        unsigned long long ok = __shfl_xor(mk, off);
        int op = __shfl_xor(mp, off);
        if (ok < mk) { mk = ok; mp = op; }
      }
      if ((tid & 63) == 0) { rk[tid >> 6] = mk; rp[tid >> 6] = mp; }
      __syncthreads();
      if (tid == 0) {
        unsigned long long fm = rk[0]; int fp = rp[0];
        for (int i = 1; i < 4; i++) if (rk[i] < fm) { fm = rk[i]; fp = rp[i]; }
        outg[r] = (int)(fm & 0xFFFFFFFFull);
        keys[fp] = ~0ull;
      }
      __syncthreads();
    }
  }
  __syncthreads();
  if (tid < KK) gidx[(size_t)bs * KK + tid] = outg[tid];
}

// ---------------------------------------------------------------------------
// Kernel 3: gather + 3x (affine with folded BN + ReLU) + max over k.
// One block per 4 centers (128 rows), 256 threads, 8k x 4oc register tiles.
// ---------------------------------------------------------------------------
template <int CIN, int COUT, bool LAST>
__device__ __forceinline__ void do_layer(
    const int tid, float (*Xb)[68], float (*Wb)[69],
    float* sa, float* sbv, float (*mm)[4],
    const float* __restrict__ w, const float* __restrict__ bb,
    const float* __restrict__ gg, const float* __restrict__ be,
    const float* __restrict__ rm, const float* __restrict__ rv,
    float* __restrict__ out2, const int bs0) {
  if (tid < COUT) {
    float a = gg[tid] / sqrtf(rv[tid] + 1e-5f);
    sa[tid] = a;
    sbv[tid] = (bb[tid] - rm[tid]) * a + be[tid];
  }
  __syncthreads();
  for (int i = tid; i < COUT * CIN; i += 256) {
    int oc = i / CIN;
    int c = i - oc * CIN;
    Wb[oc][c] = w[i] * sa[oc];
  }
  if constexpr (CIN == 67) {
    if (tid < COUT) Wb[tid][67] = 0.0f;
  }
  __syncthreads();
  constexpr int CQ = (CIN + 3) >> 2;
  const int ktile = tid >> 4;
  const int octile = tid & 15;
  const int k0 = ktile * 8;
  constexpr int NPASS = LAST ? 2 : 1;
  for (int pass = 0; pass < NPASS; pass++) {
    float acc[8][4];
#pragma unroll
    for (int i = 0; i < 8; i++)
#pragma unroll
      for (int j = 0; j < 4; j++) acc[i][j] = 0.0f;
    const int ocb = octile * 4 + pass * 64;
    for (int q = 0; q < CQ; q++) {
      float4 xq[8];
#pragma unroll
      for (int i = 0; i < 8; i++)
        xq[i] = *reinterpret_cast<const float4*>(&Xb[k0 + i][q * 4]);
#pragma unroll
      for (int j = 0; j < 4; j++) {
        const float* wr = &Wb[ocb + j][q * 4];
        float w0_ = wr[0], w1_ = wr[1], w2_ = wr[2], w3_ = wr[3];
#pragma unroll
        for (int i = 0; i < 8; i++) {
          float a_ = acc[i][j];
          a_ = fmaf(xq[i].x, w0_, a_);
          a_ = fmaf(xq[i].y, w1_, a_);
          a_ = fmaf(xq[i].z, w2_, a_);
          a_ = fmaf(xq[i].w, w3_, a_);
          acc[i][j] = a_;
        }
      }
    }
    if constexpr (!LAST) {
      __syncthreads();  // all reads of Xb done before in-place overwrite
#pragma unroll
      for (int j = 0; j < 4; j++) {
        float bias = sbv[ocb + j];
#pragma unroll
        for (int i = 0; i < 8; i++)
          Xb[k0 + i][ocb + j] = fmaxf(acc[i][j] + bias, 0.0f);
      }
      __syncthreads();
    } else {
#pragma unroll
      for (int j = 0; j < 4; j++) {
        float bias = sbv[ocb + j];
        float m = 0.0f;
#pragma unroll
        for (int i = 0; i < 8; i++)
          m = fmaxf(m, fmaxf(acc[i][j] + bias, 0.0f));
        mm[tid][j] = m;
      }
      __syncthreads();
      {
        const int ci = tid >> 6;     // local center 0..3
        const int olane = tid & 63;  // oc within pass
        const int oct = olane >> 2, jj = olane & 3;
        float m = 0.0f;
#pragma unroll
        for (int r = 0; r < 4; r++)
          m = fmaxf(m, mm[(ci * 4 + r) * 16 + oct][jj]);
        out2[((size_t)(bs0 + ci)) * 128 + pass * 64 + olane] = m;
      }
      __syncthreads();  // mm reused by next pass
    }
  }
}

__global__ __launch_bounds__(256, 2) void mlp_kernel(
    const float* __restrict__ xyz, const float* __restrict__ points,
    const float* __restrict__ newxyz, const int* __restrict__ gidx,
    const float* __restrict__ w0, const float* __restrict__ b0,
    const float* __restrict__ g0, const float* __restrict__ be0,
    const float* __restrict__ rm0, const float* __restrict__ rv0,
    const float* __restrict__ w1, const float* __restrict__ b1,
    const float* __restrict__ g1, const float* __restrict__ be1,
    const float* __restrict__ rm1, const float* __restrict__ rv1,
    const float* __restrict__ w2, const float* __restrict__ b2,
    const float* __restrict__ g2, const float* __restrict__ be2,
    const float* __restrict__ rm2, const float* __restrict__ rv2,
    float* __restrict__ out2) {
  const int tid = threadIdx.x;
  const int bs0 = blockIdx.x * 4;
  const int b = bs0 >> 9;
  __shared__ float Xb[128][68];
  __shared__ float Wb[128][69];
  __shared__ float sa[128], sbv[128];
  __shared__ float mm[256][4];
  __shared__ int sg[128];
  if (tid < 128) sg[tid] = gidx[(size_t)bs0 * KK + tid];
  __syncthreads();
  // gather point features (coalesced 64-float runs)
  for (int i = tid; i < 128 * 64; i += 256) {
    int r = i >> 6, c = i & 63;
    Xb[r][3 + c] = points[((size_t)b * NN + sg[r]) * CC + c];
  }
  // gather xyz and subtract center; zero the pad column
  if (tid < 128) {
    int ci = tid >> 5;
    int g = sg[tid];
    const float* cp = newxyz + ((size_t)bs0 + ci) * 3;
    const float* pp = xyz + ((size_t)b * NN + g) * 3;
    Xb[tid][0] = pp[0] - cp[0];
    Xb[tid][1] = pp[1] - cp[1];
    Xb[tid][2] = pp[2] - cp[2];
    Xb[tid][67] = 0.0f;
  }
  // (first barrier inside do_layer covers the gather writes)
  do_layer<67, 64, false>(tid, Xb, Wb, sa, sbv, mm, w0, b0, g0, be0, rm0, rv0, nullptr, bs0);
  do_layer<64, 64, false>(tid, Xb, Wb, sa, sbv, mm, w1, b1, g1, be1, rm1, rv1, nullptr, bs0);
  do_layer<64, 128, true>(tid, Xb, Wb, sa, sbv, mm, w2, b2, g2, be2, rm2, rv2, out2, bs0);
}

// ---------------------------------------------------------------------------
extern "C" void kernel_launch(void* const* d_in, const int* in_sizes, int n_in,
                              void* d_out, int out_size, void* d_ws, size_t ws_size,
                              hipStream_t stream) {
  const float* xyz = (const float*)d_in[0];
  const float* points = (const float*)d_in[1];
  const float* w0 = (const float*)d_in[2];
  const float* b0 = (const float*)d_in[3];
  const float* g0 = (const float*)d_in[4];
  const float* be0 = (const float*)d_in[5];
  const float* rm0 = (const float*)d_in[6];
  const float* rv0 = (const float*)d_in[7];
  const float* w1 = (const float*)d_in[8];
  const float* b1 = (const float*)d_in[9];
  const float* g1 = (const float*)d_in[10];
  const float* be1 = (const float*)d_in[11];
  const float* rm1 = (const float*)d_in[12];
  const float* rv1 = (const float*)d_in[13];
  const float* w2 = (const float*)d_in[14];
  const float* b2 = (const float*)d_in[15];
  const float* g2 = (const float*)d_in[16];
  const float* be2 = (const float*)d_in[17];
  const float* rm2 = (const float*)d_in[18];
  const float* rv2 = (const float*)d_in[19];

  float* newxyz = (float*)d_out;                       // (B, 512, 3)
  float* out2 = (float*)d_out + (size_t)BB * SS * 3;   // (B, 512, 128)
  int* gidx = (int*)d_ws;                              // (B, 512, 32)

  fps_kernel<<<BB, 256, 0, stream>>>(xyz, newxyz);
  ballq_kernel<<<BB * SS, 256, 0, stream>>>(xyz, newxyz, gidx);
  mlp_kernel<<<(BB * SS) / 4, 256, 0, stream>>>(
      xyz, points, newxyz, gidx,
      w0, b0, g0, be0, rm0, rv0,
      w1, b1, g1, be1, rm1, rv1,
      w2, b2, g2, be2, rm2, rv2,
      out2);
}

// Round 5
// 561.678 us; speedup vs baseline: 1.8626x; 1.0006x over previous
//
#include <hip/hip_runtime.h>
#include <hip/hip_bf16.h>
#include <math.h>

#define BB 16
#define NN 4096
#define SS 512
#define KK 32
#define CC 64

// ---------------------------------------------------------------------------
// Kernel 1: farthest point sampling. One block per batch, 256 threads, 16 pts/lane,
// LANE-MAJOR point assignment (p = tid*16+j) so argmax ties resolve to the
// smallest point index via lowest-lane/lowest-wave selection.
// Wave argmax via DPP (VALU pipe, ~6 dependent ops) instead of ds_swizzle
// shuffles (~700cy). Winning lane deposits (max, x, y, z, idx) in its wave's
// candidate slot BEFORE the barrier, so the post-barrier cross-wave reduce
// yields the next centroid's coordinates directly (no dependent LDS lookup).
// One barrier per iteration; parity double-buffered candidate slots.
// Replicates jnp: dist = ((dx*dx + dy*dy) + dz*dz), distance=min, argmax first-index.
// ---------------------------------------------------------------------------
template <int CTRL>
__device__ __forceinline__ float dpp_fmax_step(float m) {
  int im = __float_as_int(m);
  int t = __builtin_amdgcn_update_dpp(im, im, CTRL, 0xF, 0xF, false);
  return fmaxf(m, __int_as_float(t));
}

__global__ __launch_bounds__(256) void fps_kernel(const float* __restrict__ xyz,
                                                  float* __restrict__ newxyz) {
#pragma clang fp contract(off)
  const int b = blockIdx.x, tid = threadIdx.x;
  const int wid = tid >> 6, lane = tid & 63;
  __shared__ float sx[NN], sy[NN], sz[NN];
  __shared__ __align__(16) float cand[2][4][4];  // [par][wave][m,x,y,z]
  __shared__ int candi[2][4];
  __shared__ int sel[SS];
  const float* base = xyz + (size_t)b * NN * 3;
  for (int p = tid; p < NN; p += 256) {
    sx[p] = base[3 * p + 0];
    sy[p] = base[3 * p + 1];
    sz[p] = base[3 * p + 2];
  }
  if (tid == 0) sel[0] = 0;
  __syncthreads();
  float px[16], py[16], pz[16], d[16];
#pragma unroll
  for (int j = 0; j < 16; j++) {
    int p = tid * 16 + j;
    px[j] = sx[p]; py[j] = sy[p]; pz[j] = sz[p];
    d[j] = 1e10f;
  }
  int cur = 0;
  float cx = sx[0], cy = sy[0], cz = sz[0];
  // Reference emits `farthest` BEFORE each update; 512 outputs need only 511
  // argmax steps (sel[0] = 0).
  for (int it = 0; it < SS - 1; it++) {
    float bv = -1.0f;
    int bj = 0;
#pragma unroll
    for (int j = 0; j < 16; j++) {
      float dx = px[j] - cx, dy = py[j] - cy, dz = pz[j] - cz;
      float t0 = dx * dx, t1 = dy * dy, t2 = dz * dz;
      float dd = (t0 + t1) + t2;
      float nd = fminf(d[j], dd);
      d[j] = nd;
      // strict > keeps the smallest j (=smallest point index within lane) on ties
      if (nd > bv) { bv = nd; bj = j; }
    }
    const int bi = tid * 16 + bj;
    // wave max on the VALU pipe: row_shr 1,2,4,8 then row_bcast 15,31 -> lane 63
    float m = bv;
    m = dpp_fmax_step<0x111>(m);  // row_shr:1
    m = dpp_fmax_step<0x112>(m);  // row_shr:2
    m = dpp_fmax_step<0x114>(m);  // row_shr:4
    m = dpp_fmax_step<0x118>(m);  // row_shr:8
    m = dpp_fmax_step<0x142>(m);  // row_bcast:15
    m = dpp_fmax_step<0x143>(m);  // row_bcast:31
    const float wm = __int_as_float(__builtin_amdgcn_readlane(__float_as_int(m), 63));
    // lowest lane holding the max -> smallest point index (lane-major mapping)
    unsigned long long mask = __ballot(bv == wm);
    const int src = (int)__builtin_ctzll(mask);
    const int par = it & 1;
    if (lane == src) {
      float wx = sx[bi], wy = sy[bi], wz = sz[bi];
      *(float4*)&cand[par][wid][0] = make_float4(wm, wx, wy, wz);
      candi[par][wid] = bi;
    }
    __syncthreads();
    // all threads redundantly reduce the 4 wave candidates (strict > keeps
    // lowest wave = smallest index on exact ties)
    float4 c0 = *(const float4*)&cand[par][0][0];
    float fm = c0.x;
    float fx = c0.y, fy = c0.z, fz = c0.w;
    int fi = candi[par][0];
#pragma unroll
    for (int w = 1; w < 4; w++) {
      float4 cw = *(const float4*)&cand[par][w][0];
      int iw = candi[par][w];
      if (cw.x > fm) { fm = cw.x; fx = cw.y; fy = cw.z; fz = cw.w; fi = iw; }
    }
    cur = fi; cx = fx; cy = fy; cz = fz;
    if (tid == 0) sel[it + 1] = cur;
  }
  __syncthreads();
  for (int i = tid; i < SS * 3; i += 256) {
    int s = i / 3, c = i - s * 3;
    int g = sel[s];
    float v = (c == 0) ? sx[g] : (c == 1) ? sy[g] : sz[g];
    newxyz[((size_t)b * SS + s) * 3 + c] = v;
  }
}

// ---------------------------------------------------------------------------
// Kernel 2: ball query. One block per (b,s) center, 256 threads.
// Replicates: d = ((-2*dot) + |c|^2) + |x|^2 ; mask = d > 0.04f.
// Selected SET = (up to 32 nearest in-radius points, ties by index) filled with
// lowest-index out-of-radius points (all within first 64 indices when cnt<=32).
// Order within the group does not matter (max-pool downstream).
// ---------------------------------------------------------------------------
__global__ __launch_bounds__(256) void ballq_kernel(const float* __restrict__ xyz,
                                                    const float* __restrict__ newxyz,
                                                    int* __restrict__ gidx) {
#pragma clang fp contract(off)
  const int bs = blockIdx.x;
  const int b = bs >> 9;
  const int tid = threadIdx.x;
  __shared__ unsigned long long keys[NN];
  __shared__ int s_cnt;
  __shared__ unsigned char inflag[64];
  __shared__ int outg[KK];
  __shared__ unsigned long long rk[4];
  __shared__ int rp[4];
  if (tid == 0) s_cnt = 0;
  __syncthreads();
  const float cx = newxyz[bs * 3 + 0];
  const float cy = newxyz[bs * 3 + 1];
  const float cz = newxyz[bs * 3 + 2];
  const float csq = (cx * cx + cy * cy) + cz * cz;
  const float* base = xyz + (size_t)b * NN * 3;
  const float R2 = 0.04f;
  for (int j = 0; j < 16; j++) {
    const int p = tid + 256 * j;
    float x = base[3 * p + 0], y = base[3 * p + 1], z = base[3 * p + 2];
    float dot = (cx * x + cy * y) + cz * z;
    float ssq = (x * x + y * y) + z * z;
    float dsq = ((-2.0f * dot) + csq) + ssq;
    bool in = !(dsq > R2);
    if (p < 64) inflag[p] = in ? (unsigned char)1 : (unsigned char)0;
    if (in) {
      int pos = atomicAdd(&s_cnt, 1);
      unsigned u = __float_as_uint(dsq);
      u ^= (u >> 31) ? 0xFFFFFFFFu : 0x80000000u;  // monotonic key (handles tiny negatives)
      keys[pos] = ((unsigned long long)u << 32) | (unsigned)p;
    }
  }
  __syncthreads();
  const int cnt = s_cnt;

  if (NN - cnt < KK) {
    // reference cond branch: whole group = nearest point (min key). ~never taken.
    unsigned long long mk = ~0ull; int mp = -1;
    for (int i = tid; i < cnt; i += 256)
      if (keys[i] < mk) { mk = keys[i]; mp = i; }
    for (int off = 1; off < 64; off <<= 1) {
      unsigned long long ok = __shfl_xor(mk, off);
      int op = __shfl_xor(mp, off);
      if (ok < mk) { mk = ok; mp = op; }
    }
    if ((tid & 63) == 0) { rk[tid >> 6] = mk; rp[tid >> 6] = mp; }
    __syncthreads();
    if (tid == 0) {
      unsigned long long fm = rk[0];
      for (int i = 1; i < 4; i++) if (rk[i] < fm) fm = rk[i];
      int idx = (int)(fm & 0xFFFFFFFFull);
      for (int i = 0; i < KK; i++) outg[i] = idx;
    }
  } else if (cnt <= KK) {
    // fast path: all in-radius + lowest-index out-of-radius fill (from first 64).
    if (tid < cnt && tid < KK) outg[tid] = (int)(keys[tid] & 0xFFFFFFFFull);
    if (tid == 0) {
      int pos = cnt;
      for (int i = 0; i < 64 && pos < KK; i++)
        if (!inflag[i]) outg[pos++] = i;
    }
  } else {
    // rare: more than 32 in radius -> 32 smallest (dist,idx) keys.
    for (int r = 0; r < KK; r++) {
      unsigned long long mk = ~0ull; int mp = -1;
      for (int i = tid; i < cnt; i += 256)
        if (keys[i] < mk) { mk = keys[i]; mp = i; }
      for (int off = 1; off < 64; off <<= 1) {
        unsigned long long ok = __shfl_xor(mk, off);
        int op = __shfl_xor(mp, off);
        if (ok < mk) { mk = ok; mp = op; }
      }
      if ((tid & 63) == 0) { rk[tid >> 6] = mk; rp[tid >> 6] = mp; }
      __syncthreads();
      if (tid == 0) {
        unsigned long long fm = rk[0]; int fp = rp[0];
        for (int i = 1; i < 4; i++) if (rk[i] < fm) { fm = rk[i]; fp = rp[i]; }
        outg[r] = (int)(fm & 0xFFFFFFFFull);
        keys[fp] = ~0ull;
      }
      __syncthreads();
    }
  }
  __syncthreads();
  if (tid < KK) gidx[(size_t)bs * KK + tid] = outg[tid];
}

// ---------------------------------------------------------------------------
// Kernel 3: gather + 3x (affine with folded BN + ReLU) + max over k.
// One block per 4 centers (128 rows), 256 threads, 8k x 4oc register tiles.
// ---------------------------------------------------------------------------
template <int CIN, int COUT, bool LAST>
__device__ __forceinline__ void do_layer(
    const int tid, float (*Xb)[68], float (*Wb)[69],
    float* sa, float* sbv, float (*mm)[4],
    const float* __restrict__ w, const float* __restrict__ bb,
    const float* __restrict__ gg, const float* __restrict__ be,
    const float* __restrict__ rm, const float* __restrict__ rv,
    float* __restrict__ out2, const int bs0) {
  if (tid < COUT) {
    float a = gg[tid] / sqrtf(rv[tid] + 1e-5f);
    sa[tid] = a;
    sbv[tid] = (bb[tid] - rm[tid]) * a + be[tid];
  }
  __syncthreads();
  for (int i = tid; i < COUT * CIN; i += 256) {
    int oc = i / CIN;
    int c = i - oc * CIN;
    Wb[oc][c] = w[i] * sa[oc];
  }
  if constexpr (CIN == 67) {
    if (tid < COUT) Wb[tid][67] = 0.0f;
  }
  __syncthreads();
  constexpr int CQ = (CIN + 3) >> 2;
  const int ktile = tid >> 4;
  const int octile = tid & 15;
  const int k0 = ktile * 8;
  constexpr int NPASS = LAST ? 2 : 1;
  for (int pass = 0; pass < NPASS; pass++) {
    float acc[8][4];
#pragma unroll
    for (int i = 0; i < 8; i++)
#pragma unroll
      for (int j = 0; j < 4; j++) acc[i][j] = 0.0f;
    const int ocb = octile * 4 + pass * 64;
    for (int q = 0; q < CQ; q++) {
      float4 xq[8];
#pragma unroll
      for (int i = 0; i < 8; i++)
        xq[i] = *reinterpret_cast<const float4*>(&Xb[k0 + i][q * 4]);
#pragma unroll
      for (int j = 0; j < 4; j++) {
        const float* wr = &Wb[ocb + j][q * 4];
        float w0_ = wr[0], w1_ = wr[1], w2_ = wr[2], w3_ = wr[3];
#pragma unroll
        for (int i = 0; i < 8; i++) {
          float a_ = acc[i][j];
          a_ = fmaf(xq[i].x, w0_, a_);
          a_ = fmaf(xq[i].y, w1_, a_);
          a_ = fmaf(xq[i].z, w2_, a_);
          a_ = fmaf(xq[i].w, w3_, a_);
          acc[i][j] = a_;
        }
      }
    }
    if constexpr (!LAST) {
      __syncthreads();  // all reads of Xb done before in-place overwrite
#pragma unroll
      for (int j = 0; j < 4; j++) {
        float bias = sbv[ocb + j];
#pragma unroll
        for (int i = 0; i < 8; i++)
          Xb[k0 + i][ocb + j] = fmaxf(acc[i][j] + bias, 0.0f);
      }
      __syncthreads();
    } else {
#pragma unroll
      for (int j = 0; j < 4; j++) {
        float bias = sbv[ocb + j];
        float m = 0.0f;
#pragma unroll
        for (int i = 0; i < 8; i++)
          m = fmaxf(m, fmaxf(acc[i][j] + bias, 0.0f));
        mm[tid][j] = m;
      }
      __syncthreads();
      {
        const int ci = tid >> 6;     // local center 0..3
        const int olane = tid & 63;  // oc within pass
        const int oct = olane >> 2, jj = olane & 3;
        float m = 0.0f;
#pragma unroll
        for (int r = 0; r < 4; r++)
          m = fmaxf(m, mm[(ci * 4 + r) * 16 + oct][jj]);
        out2[((size_t)(bs0 + ci)) * 128 + pass * 64 + olane] = m;
      }
      __syncthreads();  // mm reused by next pass
    }
  }
}

__global__ __launch_bounds__(256, 2) void mlp_kernel(
    const float* __restrict__ xyz, const float* __restrict__ points,
    const float* __restrict__ newxyz, const int* __restrict__ gidx,
    const float* __restrict__ w0, const float* __restrict__ b0,
    const float* __restrict__ g0, const float* __restrict__ be0,
    const float* __restrict__ rm0, const float* __restrict__ rv0,
    const float* __restrict__ w1, const float* __restrict__ b1,
    const float* __restrict__ g1, const float* __restrict__ be1,
    const float* __restrict__ rm1, const float* __restrict__ rv1,
    const float* __restrict__ w2, const float* __restrict__ b2,
    const float* __restrict__ g2, const float* __restrict__ be2,
    const float* __restrict__ rm2, const float* __restrict__ rv2,
    float* __restrict__ out2) {
  const int tid = threadIdx.x;
  const int bs0 = blockIdx.x * 4;
  const int b = bs0 >> 9;
  __shared__ float Xb[128][68];
  __shared__ float Wb[128][69];
  __shared__ float sa[128], sbv[128];
  __shared__ float mm[256][4];
  __shared__ int sg[128];
  if (tid < 128) sg[tid] = gidx[(size_t)bs0 * KK + tid];
  __syncthreads();
  // gather point features (coalesced 64-float runs)
  for (int i = tid; i < 128 * 64; i += 256) {
    int r = i >> 6, c = i & 63;
    Xb[r][3 + c] = points[((size_t)b * NN + sg[r]) * CC + c];
  }
  // gather xyz and subtract center; zero the pad column
  if (tid < 128) {
    int ci = tid >> 5;
    int g = sg[tid];
    const float* cp = newxyz + ((size_t)bs0 + ci) * 3;
    const float* pp = xyz + ((size_t)b * NN + g) * 3;
    Xb[tid][0] = pp[0] - cp[0];
    Xb[tid][1] = pp[1] - cp[1];
    Xb[tid][2] = pp[2] - cp[2];
    Xb[tid][67] = 0.0f;
  }
  // (first barrier inside do_layer covers the gather writes)
  do_layer<67, 64, false>(tid, Xb, Wb, sa, sbv, mm, w0, b0, g0, be0, rm0, rv0, nullptr, bs0);
  do_layer<64, 64, false>(tid, Xb, Wb, sa, sbv, mm, w1, b1, g1, be1, rm1, rv1, nullptr, bs0);
  do_layer<64, 128, true>(tid, Xb, Wb, sa, sbv, mm, w2, b2, g2, be2, rm2, rv2, out2, bs0);
}

// ---------------------------------------------------------------------------
extern "C" void kernel_launch(void* const* d_in, const int* in_sizes, int n_in,
                              void* d_out, int out_size, void* d_ws, size_t ws_size,
                              hipStream_t stream) {
  const float* xyz = (const float*)d_in[0];
  const float* points = (const float*)d_in[1];
  const float* w0 = (const float*)d_in[2];
  const float* b0 = (const float*)d_in[3];
  const float* g0 = (const float*)d_in[4];
  const float* be0 = (const float*)d_in[5];
  const float* rm0 = (const float*)d_in[6];
  const float* rv0 = (const float*)d_in[7];
  const float* w1 = (const float*)d_in[8];
  const float* b1 = (const float*)d_in[9];
  const float* g1 = (const float*)d_in[10];
  const float* be1 = (const float*)d_in[11];
  const float* rm1 = (const float*)d_in[12];
  const float* rv1 = (const float*)d_in[13];
  const float* w2 = (const float*)d_in[14];
  const float* b2 = (const float*)d_in[15];
  const float* g2 = (const float*)d_in[16];
  const float* be2 = (const float*)d_in[17];
  const float* rm2 = (const float*)d_in[18];
  const float* rv2 = (const float*)d_in[19];

  float* newxyz = (float*)d_out;                       // (B, 512, 3)
  float* out2 = (float*)d_out + (size_t)BB * SS * 3;   // (B, 512, 128)
  int* gidx = (int*)d_ws;                              // (B, 512, 32)

  fps_kernel<<<BB, 256, 0, stream>>>(xyz, newxyz);
  ballq_kernel<<<BB * SS, 256, 0, stream>>>(xyz, newxyz, gidx);
  mlp_kernel<<<(BB * SS) / 4, 256, 0, stream>>>(
      xyz, points, newxyz, gidx,
      w0, b0, g0, be0, rm0, rv0,
      w1, b1, g1, be1, rm1, rv1,
      w2, b2, g2, be2, rm2, rv2,
      out2);
}

// Round 6
// 541.566 us; speedup vs baseline: 1.9318x; 1.0371x over previous
//
#include <hip/hip_runtime.h>
#include <hip/hip_bf16.h>
#include <math.h>

#define BB 16
#define NN 4096
#define SS 512
#define KK 32
#define CC 64

// ---------------------------------------------------------------------------
// Kernel 1: farthest point sampling. One block per batch, 512 threads (8 waves,
// 2/SIMD so SIMD issue slots stay full), 8 pts/lane, LANE-MAJOR (p = tid*8+j).
// Wave argmax via u64-packed (distbits<<32 | NN-1-p) DPP max chain (VALU only).
// Lane 63 deposits the wave key; after ONE barrier all lanes read the 8 keys,
// 3-step DPP max -> lane 7, one readlane -> cur. Parity double-buffered slots.
// Replicates jnp: dist = ((dx*dx + dy*dy) + dz*dz), distance=min, argmax first-index.
// ---------------------------------------------------------------------------
template <int CTRL>
__device__ __forceinline__ unsigned long long dpp_umax64(unsigned long long k) {
  int lo = (int)(unsigned)(k & 0xFFFFFFFFull);
  int hi = (int)(unsigned)(k >> 32);
  int tlo = __builtin_amdgcn_update_dpp(lo, lo, CTRL, 0xF, 0xF, false);
  int thi = __builtin_amdgcn_update_dpp(hi, hi, CTRL, 0xF, 0xF, false);
  unsigned long long t = ((unsigned long long)(unsigned)thi << 32) | (unsigned)tlo;
  return t > k ? t : k;
}

__global__ __launch_bounds__(512) void fps_kernel(const float* __restrict__ xyz,
                                                  float* __restrict__ newxyz) {
#pragma clang fp contract(off)
  const int b = blockIdx.x, tid = threadIdx.x;
  const int wid = tid >> 6, lane = tid & 63;
  __shared__ float sx[NN], sy[NN], sz[NN];
  __shared__ unsigned long long cand[2][8];
  __shared__ int sel[SS];
  const float* base = xyz + (size_t)b * NN * 3;
  for (int p = tid; p < NN; p += 512) {
    sx[p] = base[3 * p + 0];
    sy[p] = base[3 * p + 1];
    sz[p] = base[3 * p + 2];
  }
  if (tid == 0) sel[0] = 0;
  __syncthreads();
  float px[8], py[8], pz[8], d[8];
#pragma unroll
  for (int j = 0; j < 8; j++) {
    int p = tid * 8 + j;
    px[j] = sx[p]; py[j] = sy[p]; pz[j] = sz[p];
    d[j] = 1e10f;
  }
  float cx = sx[0], cy = sy[0], cz = sz[0];
  // Reference emits `farthest` BEFORE each update; 512 outputs need only 511
  // argmax steps (sel[0] = 0).
  for (int it = 0; it < SS - 1; it++) {
    float bv = -1.0f;
    int bj = 0;
#pragma unroll
    for (int j = 0; j < 8; j++) {
      float dx = px[j] - cx, dy = py[j] - cy, dz = pz[j] - cz;
      float t0 = dx * dx, t1 = dy * dy, t2 = dz * dz;
      float dd = (t0 + t1) + t2;
      float nd = fminf(d[j], dd);
      d[j] = nd;
      // strict > keeps the smallest j (=smallest point index within lane) on ties
      if (nd > bv) { bv = nd; bj = j; }
    }
    const int bp = tid * 8 + bj;
    // pack: non-negative f32 bits are order-monotone; lo = NN-1-p so equal
    // distances pick the SMALLER point index (jnp.argmax first-match).
    unsigned long long key =
        ((unsigned long long)__float_as_uint(bv) << 32) | (unsigned)(NN - 1 - bp);
    // full-wave max on the VALU pipe (row_shr 1,2,4,8 then row_bcast 15,31)
    key = dpp_umax64<0x111>(key);
    key = dpp_umax64<0x112>(key);
    key = dpp_umax64<0x114>(key);
    key = dpp_umax64<0x118>(key);
    key = dpp_umax64<0x142>(key);
    key = dpp_umax64<0x143>(key);
    const int par = it & 1;
    if (lane == 63) cand[par][wid] = key;  // lane 63 holds the wave max
    __syncthreads();
    // every lane reads one of the 8 wave keys (broadcast groups), 3-step DPP
    // max within lanes 0..7 -> lane 7 holds the block max
    unsigned long long k = cand[par][lane & 7];
    k = dpp_umax64<0x111>(k);
    k = dpp_umax64<0x112>(k);
    k = dpp_umax64<0x114>(k);
    const int lo = __builtin_amdgcn_readlane((int)(unsigned)(k & 0xFFFFFFFFull), 7);
    const int cur = NN - 1 - lo;
    cx = sx[cur]; cy = sy[cur]; cz = sz[cur];
    if (tid == 0) sel[it + 1] = cur;
  }
  __syncthreads();
  for (int i = tid; i < SS * 3; i += 512) {
    int s = i / 3, c = i - s * 3;
    int g = sel[s];
    float v = (c == 0) ? sx[g] : (c == 1) ? sy[g] : sz[g];
    newxyz[((size_t)b * SS + s) * 3 + c] = v;
  }
}

// ---------------------------------------------------------------------------
// Kernel 2: ball query. One block per (b,s) center, 256 threads.
// Replicates: d = ((-2*dot) + |c|^2) + |x|^2 ; mask = d > 0.04f.
// Selected SET = (up to 32 nearest in-radius points, ties by index) filled with
// lowest-index out-of-radius points (all within first 64 indices when cnt<=32).
// Order within the group does not matter (max-pool downstream).
// ---------------------------------------------------------------------------
__global__ __launch_bounds__(256) void ballq_kernel(const float* __restrict__ xyz,
                                                    const float* __restrict__ newxyz,
                                                    int* __restrict__ gidx) {
#pragma clang fp contract(off)
  const int bs = blockIdx.x;
  const int b = bs >> 9;
  const int tid = threadIdx.x;
  __shared__ unsigned long long keys[NN];
  __shared__ int s_cnt;
  __shared__ unsigned char inflag[64];
  __shared__ int outg[KK];
  __shared__ unsigned long long rk[4];
  __shared__ int rp[4];
  if (tid == 0) s_cnt = 0;
  __syncthreads();
  const float cx = newxyz[bs * 3 + 0];
  const float cy = newxyz[bs * 3 + 1];
  const float cz = newxyz[bs * 3 + 2];
  const float csq = (cx * cx + cy * cy) + cz * cz;
  const float* base = xyz + (size_t)b * NN * 3;
  const float R2 = 0.04f;
  for (int j = 0; j < 16; j++) {
    const int p = tid + 256 * j;
    float x = base[3 * p + 0], y = base[3 * p + 1], z = base[3 * p + 2];
    float dot = (cx * x + cy * y) + cz * z;
    float ssq = (x * x + y * y) + z * z;
    float dsq = ((-2.0f * dot) + csq) + ssq;
    bool in = !(dsq > R2);
    if (p < 64) inflag[p] = in ? (unsigned char)1 : (unsigned char)0;
    if (in) {
      int pos = atomicAdd(&s_cnt, 1);
      unsigned u = __float_as_uint(dsq);
      u ^= (u >> 31) ? 0xFFFFFFFFu : 0x80000000u;  // monotonic key (handles tiny negatives)
      keys[pos] = ((unsigned long long)u << 32) | (unsigned)p;
    }
  }
  __syncthreads();
  const int cnt = s_cnt;

  if (NN - cnt < KK) {
    // reference cond branch: whole group = nearest point (min key). ~never taken.
    unsigned long long mk = ~0ull; int mp = -1;
    for (int i = tid; i < cnt; i += 256)
      if (keys[i] < mk) { mk = keys[i]; mp = i; }
    for (int off = 1; off < 64; off <<= 1) {
      unsigned long long ok = __shfl_xor(mk, off);
      int op = __shfl_xor(mp, off);
      if (ok < mk) { mk = ok; mp = op; }
    }
    if ((tid & 63) == 0) { rk[tid >> 6] = mk; rp[tid >> 6] = mp; }
    __syncthreads();
    if (tid == 0) {
      unsigned long long fm = rk[0];
      for (int i = 1; i < 4; i++) if (rk[i] < fm) fm = rk[i];
      int idx = (int)(fm & 0xFFFFFFFFull);
      for (int i = 0; i < KK; i++) outg[i] = idx;
    }
  } else if (cnt <= KK) {
    // fast path: all in-radius + lowest-index out-of-radius fill (from first 64).
    if (tid < cnt && tid < KK) outg[tid] = (int)(keys[tid] & 0xFFFFFFFFull);
    if (tid == 0) {
      int pos = cnt;
      for (int i = 0; i < 64 && pos < KK; i++)
        if (!inflag[i]) outg[pos++] = i;
    }
  } else {
    // rare: more than 32 in radius -> 32 smallest (dist,idx) keys.
    for (int r = 0; r < KK; r++) {
      unsigned long long mk = ~0ull; int mp = -1;
      for (int i = tid; i < cnt; i += 256)
        if (keys[i] < mk) { mk = keys[i]; mp = i; }
      for (int off = 1; off < 64; off <<= 1) {
        unsigned long long ok = __shfl_xor(mk, off);
        int op = __shfl_xor(mp, off);
        if (ok < mk) { mk = ok; mp = op; }
      }
      if ((tid & 63) == 0) { rk[tid >> 6] = mk; rp[tid >> 6] = mp; }
      __syncthreads();
      if (tid == 0) {
        unsigned long long fm = rk[0]; int fp = rp[0];
        for (int i = 1; i < 4; i++) if (rk[i] < fm) { fm = rk[i]; fp = rp[i]; }
        outg[r] = (int)(fm & 0xFFFFFFFFull);
        keys[fp] = ~0ull;
      }
      __syncthreads();
    }
  }
  __syncthreads();
  if (tid < KK) gidx[(size_t)bs * KK + tid] = outg[tid];
}

// ---------------------------------------------------------------------------
// Kernel 3: gather + 3x (affine with folded BN + ReLU) + max over k.
// One block per 4 centers (128 rows), 256 threads, 8k x 4oc register tiles.
// ---------------------------------------------------------------------------
template <int CIN, int COUT, bool LAST>
__device__ __forceinline__ void do_layer(
    const int tid, float (*Xb)[68], float (*Wb)[69],
    float* sa, float* sbv, float (*mm)[4],
    const float* __restrict__ w, const float* __restrict__ bb,
    const float* __restrict__ gg, const float* __restrict__ be,
    const float* __restrict__ rm, const float* __restrict__ rv,
    float* __restrict__ out2, const int bs0) {
  if (tid < COUT) {
    float a = gg[tid] / sqrtf(rv[tid] + 1e-5f);
    sa[tid] = a;
    sbv[tid] = (bb[tid] - rm[tid]) * a + be[tid];
  }
  __syncthreads();
  for (int i = tid; i < COUT * CIN; i += 256) {
    int oc = i / CIN;
    int c = i - oc * CIN;
    Wb[oc][c] = w[i] * sa[oc];
  }
  if constexpr (CIN == 67) {
    if (tid < COUT) Wb[tid][67] = 0.0f;
  }
  __syncthreads();
  constexpr int CQ = (CIN + 3) >> 2;
  const int ktile = tid >> 4;
  const int octile = tid & 15;
  const int k0 = ktile * 8;
  constexpr int NPASS = LAST ? 2 : 1;
  for (int pass = 0; pass < NPASS; pass++) {
    float acc[8][4];
#pragma unroll
    for (int i = 0; i < 8; i++)
#pragma unroll
      for (int j = 0; j < 4; j++) acc[i][j] = 0.0f;
    const int ocb = octile * 4 + pass * 64;
    for (int q = 0; q < CQ; q++) {
      float4 xq[8];
#pragma unroll
      for (int i = 0; i < 8; i++)
        xq[i] = *reinterpret_cast<const float4*>(&Xb[k0 + i][q * 4]);
#pragma unroll
      for (int j = 0; j < 4; j++) {
        const float* wr = &Wb[ocb + j][q * 4];
        float w0_ = wr[0], w1_ = wr[1], w2_ = wr[2], w3_ = wr[3];
#pragma unroll
        for (int i = 0; i < 8; i++) {
          float a_ = acc[i][j];
          a_ = fmaf(xq[i].x, w0_, a_);
          a_ = fmaf(xq[i].y, w1_, a_);
          a_ = fmaf(xq[i].z, w2_, a_);
          a_ = fmaf(xq[i].w, w3_, a_);
          acc[i][j] = a_;
        }
      }
    }
    if constexpr (!LAST) {
      __syncthreads();  // all reads of Xb done before in-place overwrite
#pragma unroll
      for (int j = 0; j < 4; j++) {
        float bias = sbv[ocb + j];
#pragma unroll
        for (int i = 0; i < 8; i++)
          Xb[k0 + i][ocb + j] = fmaxf(acc[i][j] + bias, 0.0f);
      }
      __syncthreads();
    } else {
#pragma unroll
      for (int j = 0; j < 4; j++) {
        float bias = sbv[ocb + j];
        float m = 0.0f;
#pragma unroll
        for (int i = 0; i < 8; i++)
          m = fmaxf(m, fmaxf(acc[i][j] + bias, 0.0f));
        mm[tid][j] = m;
      }
      __syncthreads();
      {
        const int ci = tid >> 6;     // local center 0..3
        const int olane = tid & 63;  // oc within pass
        const int oct = olane >> 2, jj = olane & 3;
        float m = 0.0f;
#pragma unroll
        for (int r = 0; r < 4; r++)
          m = fmaxf(m, mm[(ci * 4 + r) * 16 + oct][jj]);
        out2[((size_t)(bs0 + ci)) * 128 + pass * 64 + olane] = m;
      }
      __syncthreads();  // mm reused by next pass
    }
  }
}

__global__ __launch_bounds__(256, 2) void mlp_kernel(
    const float* __restrict__ xyz, const float* __restrict__ points,
    const float* __restrict__ newxyz, const int* __restrict__ gidx,
    const float* __restrict__ w0, const float* __restrict__ b0,
    const float* __restrict__ g0, const float* __restrict__ be0,
    const float* __restrict__ rm0, const float* __restrict__ rv0,
    const float* __restrict__ w1, const float* __restrict__ b1,
    const float* __restrict__ g1, const float* __restrict__ be1,
    const float* __restrict__ rm1, const float* __restrict__ rv1,
    const float* __restrict__ w2, const float* __restrict__ b2,
    const float* __restrict__ g2, const float* __restrict__ be2,
    const float* __restrict__ rm2, const float* __restrict__ rv2,
    float* __restrict__ out2) {
  const int tid = threadIdx.x;
  const int bs0 = blockIdx.x * 4;
  const int b = bs0 >> 9;
  __shared__ float Xb[128][68];
  __shared__ float Wb[128][69];
  __shared__ float sa[128], sbv[128];
  __shared__ float mm[256][4];
  __shared__ int sg[128];
  if (tid < 128) sg[tid] = gidx[(size_t)bs0 * KK + tid];
  __syncthreads();
  // gather point features (coalesced 64-float runs)
  for (int i = tid; i < 128 * 64; i += 256) {
    int r = i >> 6, c = i & 63;
    Xb[r][3 + c] = points[((size_t)b * NN + sg[r]) * CC + c];
  }
  // gather xyz and subtract center; zero the pad column
  if (tid < 128) {
    int ci = tid >> 5;
    int g = sg[tid];
    const float* cp = newxyz + ((size_t)bs0 + ci) * 3;
    const float* pp = xyz + ((size_t)b * NN + g) * 3;
    Xb[tid][0] = pp[0] - cp[0];
    Xb[tid][1] = pp[1] - cp[1];
    Xb[tid][2] = pp[2] - cp[2];
    Xb[tid][67] = 0.0f;
  }
  // (first barrier inside do_layer covers the gather writes)
  do_layer<67, 64, false>(tid, Xb, Wb, sa, sbv, mm, w0, b0, g0, be0, rm0, rv0, nullptr, bs0);
  do_layer<64, 64, false>(tid, Xb, Wb, sa, sbv, mm, w1, b1, g1, be1, rm1, rv1, nullptr, bs0);
  do_layer<64, 128, true>(tid, Xb, Wb, sa, sbv, mm, w2, b2, g2, be2, rm2, rv2, out2, bs0);
}

// ---------------------------------------------------------------------------
extern "C" void kernel_launch(void* const* d_in, const int* in_sizes, int n_in,
                              void* d_out, int out_size, void* d_ws, size_t ws_size,
                              hipStream_t stream) {
  const float* xyz = (const float*)d_in[0];
  const float* points = (const float*)d_in[1];
  const float* w0 = (const float*)d_in[2];
  const float* b0 = (const float*)d_in[3];
  const float* g0 = (const float*)d_in[4];
  const float* be0 = (const float*)d_in[5];
  const float* rm0 = (const float*)d_in[6];
  const float* rv0 = (const float*)d_in[7];
  const float* w1 = (const float*)d_in[8];
  const float* b1 = (const float*)d_in[9];
  const float* g1 = (const float*)d_in[10];
  const float* be1 = (const float*)d_in[11];
  const float* rm1 = (const float*)d_in[12];
  const float* rv1 = (const float*)d_in[13];
  const float* w2 = (const float*)d_in[14];
  const float* b2 = (const float*)d_in[15];
  const float* g2 = (const float*)d_in[16];
  const float* be2 = (const float*)d_in[17];
  const float* rm2 = (const float*)d_in[18];
  const float* rv2 = (const float*)d_in[19];

  float* newxyz = (float*)d_out;                       // (B, 512, 3)
  float* out2 = (float*)d_out + (size_t)BB * SS * 3;   // (B, 512, 128)
  int* gidx = (int*)d_ws;                              // (B, 512, 32)

  fps_kernel<<<BB, 512, 0, stream>>>(xyz, newxyz);
  ballq_kernel<<<BB * SS, 256, 0, stream>>>(xyz, newxyz, gidx);
  mlp_kernel<<<(BB * SS) / 4, 256, 0, stream>>>(
      xyz, points, newxyz, gidx,
      w0, b0, g0, be0, rm0, rv0,
      w1, b1, g1, be1, rm1, rv1,
      w2, b2, g2, be2, rm2, rv2,
      out2);
}